// Round 7
// baseline (22133.005 us; speedup 1.0000x reference)
//
#include <hip/hip_runtime.h>

#define B 64
#define T 256
#define H 512
#define G4 2048     // 4*H
#define D0 128
#define NL 6
#define TC 64       // timestep chunk
#define NCHUNK (T / TC)
#define NBLK_R 128
#define FSTRIDE 16  // u32 stride between per-block flags (64B lines)

// ===========================================================================
// xp_gemm — used ONCE (layer 0 chunk 0 prologue). Proven in rounds 3-6.
// ===========================================================================
__global__ void __launch_bounds__(512) xp_gemm(
    const float* __restrict__ x, int Din, int dqs,
    const float* __restrict__ Wih,
    const float* __restrict__ bih, const float* __restrict__ bhh,
    float* __restrict__ xp, int t0)
{
  __shared__ float x_s[64 * 129 * 4];
  const int tid  = threadIdx.x;
  const int lane = tid & 63;
  const int w    = __builtin_amdgcn_readfirstlane(tid >> 6);
  const int s    = (int)blockIdx.x >> 2;
  const int t    = t0 + s;
  const int rt   = ((int)blockIdx.x & 3) * 512;
  const int Dq   = Din >> 2;
  const int su   = Dq + 1;

  const int nf4 = 64 * Dq;
  for (int f = tid; f < nf4; f += 512) {
    int b = f >> dqs;
    int u = f & (Dq - 1);
    float4 v = *(const float4*)(x + ((size_t)b * T + t) * Din + u * 4);
    *(float4*)&x_s[(b * su + u) * 4] = v;
  }
  __syncthreads();

  const float* xrow = &x_s[lane * su * 4];
  for (int grp = 0; grp < 8; ++grp) {
    const int r0 = rt + w * 64 + grp * 8;
    float acc[8];
#pragma unroll
    for (int rr = 0; rr < 8; ++rr) acc[rr] = bih[r0 + rr] + bhh[r0 + rr];
#pragma unroll 4
    for (int q = 0; q < Dq; ++q) {
      float4 hv = *(const float4*)(xrow + q * 4);
#pragma unroll
      for (int rr = 0; rr < 8; ++rr) {
        float4 wv = *(const float4*)(Wih + (size_t)(r0 + rr) * Din + q * 4);
        acc[rr] = fmaf(hv.w, wv.w,
                  fmaf(hv.z, wv.z, fmaf(hv.y, wv.y, fmaf(hv.x, wv.x, acc[rr]))));
      }
    }
    float* op = xp + ((size_t)s * G4 + r0) * 64 + lane;
#pragma unroll
    for (int rr = 0; rr < 8; ++rr) op[rr * 64] = acc[rr];
  }
}

// ===========================================================================
// lstm_rec v3 — k-split GEMM + in-shadow xp fold.
//  * 128 blocks x 1024 threads (block = 4 hidden cols -> 16 gate rows).
//    16 waves = 4 k-slices x 4 row-quads (quad == gate). Wave reads ONLY its
//    128-wide k-slice of h (32 ds_read_b128) and reuses it over 4 rows ->
//    block LDS read volume drops 16x vs round-6 (the measured 6.8us/step
//    LDS-pipe bound). Partials reduced via g_par[4][16][64] (16KB).
//  * xp FOLD: after flag-publish (the stall shadow), the block computes next
//    chunk's xp for ITS OWN 16 rows with the same k-split structure, staging
//    the x-slab into the then-dead h_s. In-place xp: each (row,lane) is
//    read (reduce) then written (fold) by the SAME thread; rows block-private.
//  * Barrier: round-6 proven flag array, unchanged. h publish: sc1, unchanged.
// ===========================================================================
__global__ void __launch_bounds__(1024, 4) lstm_rec(
    float* xpbuf, const float* __restrict__ Whh,
    float* __restrict__ y, float* __restrict__ cbuf,
    int t0, unsigned gbase, unsigned* __restrict__ flags,
    int haveFold, const float* __restrict__ xsrc, int fdqs,
    const float* __restrict__ Wf,
    const float* __restrict__ bihf, const float* __restrict__ bhhf,
    int tf0)
{
  __shared__ float h_s[64 * 129 * 4];   // 132096 B (also fold's x stage)
  __shared__ float g_par[4][16][64];    // 16384 B  (k-slice partials)
  __shared__ float s_s[16][64];         // 4096 B   (gate sums)

  const int tid  = threadIdx.x;
  const int lane = tid & 63;            // batch
  const int w    = tid >> 6;            // wave 0..15
  const int wl   = __builtin_amdgcn_readfirstlane(w);
  const int ks   = wl & 3;              // k-slice 0..3 (128 k each)
  const int rq   = wl >> 2;             // row-quad 0..3 == gate
  const int blk  = (int)blockIdx.x;
  const int j0   = blk * 4;             // owned hidden cols j0..j0+3

  // rec GEMM W row pointers (wave-uniform -> s_load), k-slice offset folded
  const float* Wp0 = Whh + (size_t)(rq * H + j0 + 0) * H + ks * 128;
  const float* Wp1 = Whh + (size_t)(rq * H + j0 + 1) * H + ks * 128;
  const float* Wp2 = Whh + (size_t)(rq * H + j0 + 2) * H + ks * 128;
  const float* Wp3 = Whh + (size_t)(rq * H + j0 + 3) * H + ks * 128;

  // reduce-row constants: this thread reduces row w (gate w>>2, col w&3)
  const int growM = (w >> 2) * H + j0 + (w & 3);
  const size_t xpStep = (size_t)G4 * 64;
  float* xpR = xpbuf + (size_t)growM * 64 + lane;   // read AND fold-write

  // fold constants
  const int funits = 1 << fdqs;         // K_f/4 float4 units (32 or 128)
  const int fsu    = funits + 1;        // padded LDS stride
  const int fuq    = funits >> 2;       // slice units per wave
  const int Kf     = funits * 4;
  const float* Wf0 = Wf + (size_t)(rq * H + j0 + 0) * Kf + ks * funits;
  const float* Wf1 = Wf + (size_t)(rq * H + j0 + 1) * Kf + ks * funits;
  const float* Wf2 = Wf + (size_t)(rq * H + j0 + 2) * Kf + ks * funits;
  const float* Wf3 = Wf + (size_t)(rq * H + j0 + 3) * Kf + ks * funits;
  const float biasF = haveFold ? (bihf[growM] + bhhf[growM]) : 0.f;

  // pointwise ownership: b = tid>>2, col = j0 + (tid&3)
  const int pb = tid >> 2, pcj = tid & 3;
  float creg = 0.f;
  if (t0 > 0 && tid < 256) creg = cbuf[pb * H + j0 + pcj];

  for (int s = 0; s < TC; ++s) {
    const int t = t0 + s;

    if (t > 0) {
      if (s > 0) {   // h(t-1) from a previous launch needs no wait
        if (tid < NBLK_R) {
          const unsigned tgt = gbase + (unsigned)s;
          while ((int)(__hip_atomic_load(&flags[tid * FSTRIDE],
                                         __ATOMIC_RELAXED,
                                         __HIP_MEMORY_SCOPE_AGENT) - tgt) < 0)
            __builtin_amdgcn_s_sleep(1);
        }
        __syncthreads();
      }
      // stage h(t-1): 128KB, coalesced 16B loads, odd-stride LDS
#pragma unroll
      for (int i = 0; i < 8; ++i) {
        int f = tid + 1024 * i;
        int b = f >> 7, u = f & 127;
        float4 v = *(const float4*)(y + ((size_t)b * T + (t - 1)) * H + u * 4);
        *(float4*)&h_s[(b * 129 + u) * 4] = v;
      }
      __syncthreads();
      // k-split GEMM: this wave's 128-wide k-slice x 4 rows
      const float* hrow = &h_s[(lane * 129 + ks * 32) * 4];
      float a0 = 0.f, a1 = 0.f, a2 = 0.f, a3 = 0.f;
#pragma unroll 8
      for (int u = 0; u < 32; ++u) {
        float4 hv = *(const float4*)(hrow + u * 4);
        float4 w0 = *(const float4*)(Wp0 + u * 4);
        float4 w1 = *(const float4*)(Wp1 + u * 4);
        float4 w2 = *(const float4*)(Wp2 + u * 4);
        float4 w3 = *(const float4*)(Wp3 + u * 4);
        a0 = fmaf(hv.w,w0.w, fmaf(hv.z,w0.z, fmaf(hv.y,w0.y, fmaf(hv.x,w0.x, a0))));
        a1 = fmaf(hv.w,w1.w, fmaf(hv.z,w1.z, fmaf(hv.y,w1.y, fmaf(hv.x,w1.x, a1))));
        a2 = fmaf(hv.w,w2.w, fmaf(hv.z,w2.z, fmaf(hv.y,w2.y, fmaf(hv.x,w2.x, a2))));
        a3 = fmaf(hv.w,w3.w, fmaf(hv.z,w3.z, fmaf(hv.y,w3.y, fmaf(hv.x,w3.x, a3))));
      }
      g_par[ks][rq * 4 + 0][lane] = a0;
      g_par[ks][rq * 4 + 1][lane] = a1;
      g_par[ks][rq * 4 + 2][lane] = a2;
      g_par[ks][rq * 4 + 3][lane] = a3;
    }
    __syncthreads();

    // reduce row w: xp + 4 k-slice partials (coalesced, conflict-free)
    float sum = xpR[(size_t)s * xpStep];
    if (t > 0)
      sum += (g_par[0][w][lane] + g_par[1][w][lane]) +
             (g_par[2][w][lane] + g_par[3][w][lane]);
    s_s[w][lane] = sum;

    // fold stage into h_s (dead after GEMM; readers sync'd below)
    if (haveFold) {
      const int tf = tf0 + s;
      for (int f = tid; f < (64 << fdqs); f += 1024) {
        int b = f >> fdqs, u = f & (funits - 1);
        float4 v = *(const float4*)(xsrc + ((size_t)b * T + tf) * Kf + u * 4);
        *(float4*)&h_s[(b * fsu + u) * 4] = v;
      }
    }
    __syncthreads();

    if (tid < 256) {
      float gi = s_s[ 0 + pcj][pb];
      float gf = s_s[ 4 + pcj][pb];
      float gg = s_s[ 8 + pcj][pb];
      float go = s_s[12 + pcj][pb];
      float iv = 1.f / (1.f + expf(-gi));
      float fv = 1.f / (1.f + expf(-gf));
      float gv = tanhf(gg);
      float ov = 1.f / (1.f + expf(-go));
      creg = fv * creg + iv * gv;
      float hv = ov * tanhf(creg);
      // publish h(t) at the coherence point (sc1 write-through)
      __hip_atomic_store(&y[((size_t)pb * T + t) * H + j0 + pcj], hv,
                         __ATOMIC_RELAXED, __HIP_MEMORY_SCOPE_AGENT);
    }
    __syncthreads();   // drains publish stores
    if (tid == 0)
      __hip_atomic_store(&flags[blk * FSTRIDE], gbase + (unsigned)s + 1u,
                         __ATOMIC_RELAXED, __HIP_MEMORY_SCOPE_AGENT);

    // ---- xp fold, in the publish->wait shadow ----
    if (haveFold) {
      const float* frow = &h_s[(lane * fsu + ks * fuq) * 4];
      float a0 = 0.f, a1 = 0.f, a2 = 0.f, a3 = 0.f;
#pragma unroll 4
      for (int u = 0; u < fuq; ++u) {
        float4 hv = *(const float4*)(frow + u * 4);
        float4 w0 = *(const float4*)(Wf0 + u * 4);
        float4 w1 = *(const float4*)(Wf1 + u * 4);
        float4 w2 = *(const float4*)(Wf2 + u * 4);
        float4 w3 = *(const float4*)(Wf3 + u * 4);
        a0 = fmaf(hv.w,w0.w, fmaf(hv.z,w0.z, fmaf(hv.y,w0.y, fmaf(hv.x,w0.x, a0))));
        a1 = fmaf(hv.w,w1.w, fmaf(hv.z,w1.z, fmaf(hv.y,w1.y, fmaf(hv.x,w1.x, a1))));
        a2 = fmaf(hv.w,w2.w, fmaf(hv.z,w2.z, fmaf(hv.y,w2.y, fmaf(hv.x,w2.x, a2))));
        a3 = fmaf(hv.w,w3.w, fmaf(hv.z,w3.z, fmaf(hv.y,w3.y, fmaf(hv.x,w3.x, a3))));
      }
      g_par[ks][rq * 4 + 0][lane] = a0;
      g_par[ks][rq * 4 + 1][lane] = a1;
      g_par[ks][rq * 4 + 2][lane] = a2;
      g_par[ks][rq * 4 + 3][lane] = a3;
      __syncthreads();
      float sf = biasF + (g_par[0][w][lane] + g_par[1][w][lane]) +
                         (g_par[2][w][lane] + g_par[3][w][lane]);
      xpR[(size_t)s * xpStep] = sf;   // in-place: same thread that read it
      // next iter's poll+stage syncs order g_par/h_s reuse
    }
  }
  if (tid < 256) cbuf[pb * H + j0 + pcj] = creg;
}

// ===========================================================================
// Final FC on last timestep.
// ===========================================================================
__global__ void __launch_bounds__(640) fc_kernel(
    const float* __restrict__ y, const float* __restrict__ w,
    const float* __restrict__ bias, float* __restrict__ out)
{
  int tid = threadIdx.x;
  if (tid >= 640) return;
  int b = tid / 10, o = tid - b * 10;
  const float* yr = y + (size_t)b * (T * H) + (size_t)(T - 1) * H;
  const float* wr = w + (size_t)o * H;
  float acc = bias[o];
  for (int k = 0; k < H; ++k) acc = fmaf(yr[k], wr[k], acc);
  out[b * 10 + o] = acc;
}

extern "C" void kernel_launch(void* const* d_in, const int* in_sizes, int n_in,
                              void* d_out, int out_size, void* d_ws,
                              size_t ws_size, hipStream_t stream)
{
  const float* x    = (const float*)d_in[0];
  const float* Wih0 = (const float*)d_in[1];
  const float* WihR = (const float*)d_in[2];
  const float* Whh  = (const float*)d_in[3];
  const float* bih  = (const float*)d_in[4];
  const float* bhh  = (const float*)d_in[5];
  const float* fcw  = (const float*)d_in[6];
  const float* fcb  = (const float*)d_in[7];
  float* out = (float*)d_out;

  // ws: [0,16K) flags; cbuf [B][H]; xp [TC][G4][B] (single, folded in place);
  //     y [B][T][H]
  unsigned* flags = (unsigned*)d_ws;
  float* cbuf = (float*)((char*)d_ws + 16384);
  float* xpb  = (float*)((char*)d_ws + 16384 + (size_t)B * H * 4);
  float* y    = xpb + (size_t)TC * G4 * B;

  hipMemsetAsync(d_ws, 0, 16384, stream);  // flags monotonic within a call

  for (int l = 0; l < NL; ++l) {
    const float* Whh_l = Whh + (size_t)l * G4 * H;
    for (int c = 0; c < NCHUNK; ++c) {
      int t0 = c * TC;
      unsigned gbase = (unsigned)((l * NCHUNK + c) * TC);
      if (l == 0 && c == 0)
        xp_gemm<<<TC * 4, 512, 0, stream>>>(x, D0, 5, Wih0, bih, bhh, xpb, 0);

      // fold target: (l, c+1) for c<3; (l+1, 0) for c==3; none for (5,3)
      int haveFold; const float* xsrc; int fdqs;
      const float* Wf; const float* bihf; const float* bhhf; int tf0;
      if (c < NCHUNK - 1) {
        haveFold = 1;
        xsrc = (l == 0) ? x : y;
        fdqs = (l == 0) ? 5 : 7;
        Wf   = (l == 0) ? Wih0 : (WihR + (size_t)(l - 1) * G4 * H);
        bihf = bih + l * G4; bhhf = bhh + l * G4;
        tf0  = t0 + TC;
      } else if (l < NL - 1) {
        haveFold = 1;
        xsrc = y; fdqs = 7;
        Wf   = WihR + (size_t)l * G4 * H;      // layer l+1's W_ih
        bihf = bih + (l + 1) * G4; bhhf = bhh + (l + 1) * G4;
        tf0  = 0;
      } else {
        haveFold = 0; xsrc = x; fdqs = 7;
        Wf = Wih0; bihf = bih; bhhf = bhh; tf0 = 0;
      }
      lstm_rec<<<NBLK_R, 1024, 0, stream>>>(
          xpb, Whh_l, y, cbuf, t0, gbase, flags,
          haveFold, xsrc, fdqs, Wf, bihf, bhhf, tf0);
    }
  }
  fc_kernel<<<1, 640, 0, stream>>>(y, fcw, fcb, out);
}

// Round 8
// 17654.588 us; speedup vs baseline: 1.2537x; 1.2537x over previous
//
#include <hip/hip_runtime.h>

#define B 64
#define T 256
#define H 512
#define G4 2048     // 4*H
#define D0 128
#define NL 6
#define TC 64       // timestep chunk
#define NCHUNK (T / TC)
#define NBLK_R 128
#define FSTRIDE 16  // u32 stride between per-block flags (64B lines)

// ===========================================================================
// xp_gemm3 — LDS-broadcast GEMM (replaces scalar-W xp_gemm, which ran at 15%
// of VALU roofline due to scalar-cache thrash).
// Grid 512 = 16 row-tiles(128) x 32 t-pairs; 1024 thr; lane = batch.
// Per k-tile(128): stage W[128r][32q] (64KB) + x[2t][64b][32q+pad] (67.5KB)
// coalesced; compute: x quad per-lane (conflict-free odd stride), W quads
// wave-uniform broadcast ds_read_b128 (conflict-free); 64 fmac per x-read.
// Bias added in epilogue (reassoc ~1e-6, invisible at bf16 out granularity).
// ===========================================================================
__global__ void __launch_bounds__(1024) xp_gemm3(
    const float* __restrict__ xsrc, int Kf,
    const float* __restrict__ Wf,
    const float* __restrict__ bih, const float* __restrict__ bhh,
    float* __restrict__ xp, int t0)
{
  __shared__ float x_s[2 * 64 * 33 * 4];   // 67584 B
  __shared__ float w_s[128 * 32 * 4];      // 65536 B
  const int tid  = threadIdx.x;
  const int lane = tid & 63;
  const int wl   = __builtin_amdgcn_readfirstlane(tid >> 6);
  const int t_l  = wl & 1;                 // wave's timestep within pair
  const int rb   = (wl >> 1) * 16;         // wave's 16 rows within tile
  const int bx   = (int)blockIdx.x;
  const int rt   = (bx >> 5) * 128;        // row tile base
  const int tg   = bx & 31;                // t-pair index
  const int nkt  = Kf >> 7;                // 1 (layer 0) or 4

  float acc[16];
#pragma unroll
  for (int r = 0; r < 16; ++r) acc[r] = 0.f;

  for (int kt = 0; kt < nkt; ++kt) {
    // stage W tile [128 r][32 q], coalesced float4
#pragma unroll
    for (int i = 0; i < 4; ++i) {
      int f = tid + 1024 * i;
      int r = f >> 5, q = f & 31;
      float4 v = *(const float4*)(Wf + (size_t)(rt + r) * Kf + kt * 128 + q * 4);
      *(float4*)&w_s[(r * 32 + q) * 4] = v;
    }
    // stage x tile [2 t][64 b][32 q], odd-stride pad
#pragma unroll
    for (int i = 0; i < 4; ++i) {
      int f = tid + 1024 * i;
      int tl = f >> 11, b = (f >> 5) & 63, q = f & 31;
      int t = t0 + tg * 2 + tl;
      float4 v = *(const float4*)(xsrc + ((size_t)b * T + t) * Kf + kt * 128 + q * 4);
      *(float4*)&x_s[((tl * 64 + b) * 33 + q) * 4] = v;
    }
    __syncthreads();
    const float* xrow = &x_s[(t_l * 64 + lane) * 33 * 4];
#pragma unroll 2
    for (int q = 0; q < 32; ++q) {
      float4 xq = *(const float4*)(xrow + q * 4);
#pragma unroll
      for (int r = 0; r < 16; ++r) {
        float4 wq = *(const float4*)&w_s[((rb + r) * 32 + q) * 4];  // broadcast
        acc[r] = fmaf(xq.w, wq.w,
                 fmaf(xq.z, wq.z, fmaf(xq.y, wq.y, fmaf(xq.x, wq.x, acc[r]))));
      }
    }
    __syncthreads();
  }

  const int s_l = tg * 2 + t_l;            // chunk-local timestep
#pragma unroll
  for (int r = 0; r < 16; ++r) {
    int row = rt + rb + r;
    xp[((size_t)s_l * G4 + row) * 64 + lane] = acc[r] + bih[row] + bhh[row];
  }
}

// ===========================================================================
// lstm_rec — round-7 kernel with the fold AMPUTATED (the haveFold==0 path,
// which ran correctly for dispatch (5,3)). Isolates the k-split GEMM:
// 16 waves = 4 k-slices x 4 gates; wave reads only its 128-wide k-slice of
// h (32 ds_read_b128) reused over 4 rows -> 16x less LDS volume than the
// round-5 full-K version. Flag barrier / sc1 publish proven unchanged.
// ===========================================================================
__global__ void __launch_bounds__(1024, 4) lstm_rec(
    const float* __restrict__ xpbuf, const float* __restrict__ Whh,
    float* __restrict__ y, float* __restrict__ cbuf,
    int t0, unsigned gbase, unsigned* __restrict__ flags)
{
  __shared__ float h_s[64 * 129 * 4];   // 132096 B, odd float4 stride
  __shared__ float g_par[4][16][64];    // 16384 B  (k-slice partials)
  __shared__ float s_s[16][64];         // 4096 B   (gate sums)

  const int tid  = threadIdx.x;
  const int lane = tid & 63;            // batch
  const int w    = tid >> 6;            // wave 0..15
  const int wl   = __builtin_amdgcn_readfirstlane(w);
  const int ks   = wl & 3;              // k-slice 0..3 (128 k each)
  const int rq   = wl >> 2;             // row-quad 0..3 == gate
  const int blk  = (int)blockIdx.x;
  const int j0   = blk * 4;             // owned hidden cols j0..j0+3

  const float* Wp0 = Whh + (size_t)(rq * H + j0 + 0) * H + ks * 128;
  const float* Wp1 = Whh + (size_t)(rq * H + j0 + 1) * H + ks * 128;
  const float* Wp2 = Whh + (size_t)(rq * H + j0 + 2) * H + ks * 128;
  const float* Wp3 = Whh + (size_t)(rq * H + j0 + 3) * H + ks * 128;

  const int growM = (w >> 2) * H + j0 + (w & 3);  // this thread's reduce row
  const size_t xpStep = (size_t)G4 * 64;
  const float* xpR = xpbuf + (size_t)growM * 64 + lane;

  const int pb = tid >> 2, pcj = tid & 3;
  float creg = 0.f;
  if (t0 > 0 && tid < 256) creg = cbuf[pb * H + j0 + pcj];

  for (int s = 0; s < TC; ++s) {
    const int t = t0 + s;

    if (t > 0) {
      if (s > 0) {   // h(t-1) from a previous launch needs no wait
        if (tid < NBLK_R) {
          const unsigned tgt = gbase + (unsigned)s;
          while ((int)(__hip_atomic_load(&flags[tid * FSTRIDE],
                                         __ATOMIC_RELAXED,
                                         __HIP_MEMORY_SCOPE_AGENT) - tgt) < 0)
            __builtin_amdgcn_s_sleep(1);
        }
        __syncthreads();
      }
      // stage h(t-1): 128KB, coalesced 16B loads, odd-stride LDS
#pragma unroll
      for (int i = 0; i < 8; ++i) {
        int f = tid + 1024 * i;
        int b = f >> 7, u = f & 127;
        float4 v = *(const float4*)(y + ((size_t)b * T + (t - 1)) * H + u * 4);
        *(float4*)&h_s[(b * 129 + u) * 4] = v;
      }
      __syncthreads();
      // k-split GEMM: this wave's 128-wide k-slice x 4 rows
      const float* hrow = &h_s[(lane * 129 + ks * 32) * 4];
      float a0 = 0.f, a1 = 0.f, a2 = 0.f, a3 = 0.f;
#pragma unroll 8
      for (int u = 0; u < 32; ++u) {
        float4 hv = *(const float4*)(hrow + u * 4);
        float4 w0 = *(const float4*)(Wp0 + u * 4);
        float4 w1 = *(const float4*)(Wp1 + u * 4);
        float4 w2 = *(const float4*)(Wp2 + u * 4);
        float4 w3 = *(const float4*)(Wp3 + u * 4);
        a0 = fmaf(hv.w,w0.w, fmaf(hv.z,w0.z, fmaf(hv.y,w0.y, fmaf(hv.x,w0.x, a0))));
        a1 = fmaf(hv.w,w1.w, fmaf(hv.z,w1.z, fmaf(hv.y,w1.y, fmaf(hv.x,w1.x, a1))));
        a2 = fmaf(hv.w,w2.w, fmaf(hv.z,w2.z, fmaf(hv.y,w2.y, fmaf(hv.x,w2.x, a2))));
        a3 = fmaf(hv.w,w3.w, fmaf(hv.z,w3.z, fmaf(hv.y,w3.y, fmaf(hv.x,w3.x, a3))));
      }
      g_par[ks][rq * 4 + 0][lane] = a0;
      g_par[ks][rq * 4 + 1][lane] = a1;
      g_par[ks][rq * 4 + 2][lane] = a2;
      g_par[ks][rq * 4 + 3][lane] = a3;
    }
    __syncthreads();

    // reduce row w: xp + 4 k-slice partials
    float sum = xpR[(size_t)s * xpStep];
    if (t > 0)
      sum += (g_par[0][w][lane] + g_par[1][w][lane]) +
             (g_par[2][w][lane] + g_par[3][w][lane]);
    s_s[w][lane] = sum;
    __syncthreads();

    if (tid < 256) {
      float gi = s_s[ 0 + pcj][pb];
      float gf = s_s[ 4 + pcj][pb];
      float gg = s_s[ 8 + pcj][pb];
      float go = s_s[12 + pcj][pb];
      float iv = 1.f / (1.f + expf(-gi));
      float fv = 1.f / (1.f + expf(-gf));
      float gv = tanhf(gg);
      float ov = 1.f / (1.f + expf(-go));
      creg = fv * creg + iv * gv;
      float hv = ov * tanhf(creg);
      // publish h(t) at the coherence point (sc1 write-through)
      __hip_atomic_store(&y[((size_t)pb * T + t) * H + j0 + pcj], hv,
                         __ATOMIC_RELAXED, __HIP_MEMORY_SCOPE_AGENT);
    }
    __syncthreads();   // drains publish stores
    if (tid == 0)
      __hip_atomic_store(&flags[blk * FSTRIDE], gbase + (unsigned)s + 1u,
                         __ATOMIC_RELAXED, __HIP_MEMORY_SCOPE_AGENT);
  }
  if (tid < 256) cbuf[pb * H + j0 + pcj] = creg;
}

// ===========================================================================
// Final FC on last timestep.
// ===========================================================================
__global__ void __launch_bounds__(640) fc_kernel(
    const float* __restrict__ y, const float* __restrict__ w,
    const float* __restrict__ bias, float* __restrict__ out)
{
  int tid = threadIdx.x;
  if (tid >= 640) return;
  int b = tid / 10, o = tid - b * 10;
  const float* yr = y + (size_t)b * (T * H) + (size_t)(T - 1) * H;
  const float* wr = w + (size_t)o * H;
  float acc = bias[o];
  for (int k = 0; k < H; ++k) acc = fmaf(yr[k], wr[k], acc);
  out[b * 10 + o] = acc;
}

extern "C" void kernel_launch(void* const* d_in, const int* in_sizes, int n_in,
                              void* d_out, int out_size, void* d_ws,
                              size_t ws_size, hipStream_t stream)
{
  const float* x    = (const float*)d_in[0];
  const float* Wih0 = (const float*)d_in[1];
  const float* WihR = (const float*)d_in[2];
  const float* Whh  = (const float*)d_in[3];
  const float* bih  = (const float*)d_in[4];
  const float* bhh  = (const float*)d_in[5];
  const float* fcw  = (const float*)d_in[6];
  const float* fcb  = (const float*)d_in[7];
  float* out = (float*)d_out;

  // ws: [0,16K) flags; cbuf [B][H]; xp [TC][G4][B]; y [B][T][H]  (~64 MB,
  // same footprint proven since round 5)
  unsigned* flags = (unsigned*)d_ws;
  float* cbuf = (float*)((char*)d_ws + 16384);
  float* xpb  = (float*)((char*)d_ws + 16384 + (size_t)B * H * 4);
  float* y    = xpb + (size_t)TC * G4 * B;

  hipMemsetAsync(d_ws, 0, 16384, stream);  // flags monotonic within a call

  for (int l = 0; l < NL; ++l) {
    const float* Whh_l = Whh + (size_t)l * G4 * H;
    const float* Wih_l = (l == 0) ? Wih0 : (WihR + (size_t)(l - 1) * G4 * H);
    const float* xsrc  = (l == 0) ? x : y;   // y rows for chunk c still hold
    const int    Kf    = (l == 0) ? D0 : H;  // layer l-1 when xp(l,c) runs
    for (int c = 0; c < NCHUNK; ++c) {
      int t0 = c * TC;
      unsigned gbase = (unsigned)((l * NCHUNK + c) * TC);
      xp_gemm3<<<512, 1024, 0, stream>>>(xsrc, Kf, Wih_l,
                                         bih + l * G4, bhh + l * G4, xpb, t0);
      lstm_rec<<<NBLK_R, 1024, 0, stream>>>(xpb, Whh_l, y, cbuf, t0, gbase,
                                            flags);
    }
  }
  fc_kernel<<<1, 640, 0, stream>>>(y, fcw, fcb, out);
}

// Round 9
// 17101.611 us; speedup vs baseline: 1.2942x; 1.0323x over previous
//
#include <hip/hip_runtime.h>

#define B 64
#define T 256
#define H 512
#define G4 2048     // 4*H
#define D0 128
#define NL 6
#define NBLK_P 192            // 6 layers x 32 col-groups
#define GTOT (T + NL - 1)     // 261 global pipeline steps
#define FSTRIDE 16            // u32 stride between per-block flags (64B)
#define SLABF (64 * 65 * 4)   // floats per 64KB h-slab [64 b][64 q], stride 65

typedef float f32x4 __attribute__((ext_vector_type(4)));

// Coherent 16B load: sc0+sc1 = system-scope read -> bypasses the (possibly
// stale) per-XCD L2. Needed because h ring slots reuse addresses every 2 steps.
#define CLOAD(dst, p) \
  asm volatile("global_load_dwordx4 %0, %1, off sc0 sc1" : "=&v"(dst) : "v"(p))
// Rule #18: sched_barrier after the waitcnt so ds_writes can't hoist above it.
#define VMWAIT do { asm volatile("s_waitcnt vmcnt(0)" ::: "memory"); \
                    __builtin_amdgcn_sched_barrier(0); } while (0)
#define ISSUE4(src) \
  CLOAD(r0, (src) + go0); CLOAD(r1, (src) + go1); \
  CLOAD(r2, (src) + go2); CLOAD(r3, (src) + go3)
#define WRITE4(slab) \
  VMWAIT; \
  *(f32x4*)&(slab)[lo0] = r0; *(f32x4*)&(slab)[lo1] = r1; \
  *(f32x4*)&(slab)[lo2] = r2; *(f32x4*)&(slab)[lo3] = r3

// One GEMM phase: this wave's ks-slice (QS quads) x its 16 gate-rows.
// W reads are wave-uniform -> s_load; slab reads odd-stride -> conflict-lite.
template<int QS, int SU, int WK>
__device__ __forceinline__ void gemm_ph(const float* slab, const float* W0,
                                        int ks, int lane, float (&acc)[16])
{
  const float* hrow = slab + (lane * SU + ks * QS) * 4;
  const float* Wk   = W0 + ks * QS * 4;
#pragma unroll 2
  for (int u = 0; u < QS; ++u) {
    float4 hv = *(const float4*)(hrow + u * 4);
#pragma unroll
    for (int r = 0; r < 16; ++r) {
      float4 wq = *(const float4*)(Wk + (size_t)r * WK + u * 4);
      acc[r] = fmaf(hv.w, wq.w, fmaf(hv.z, wq.z,
               fmaf(hv.y, wq.y, fmaf(hv.x, wq.x, acc[r]))));
    }
  }
}

// ===========================================================================
// lstm_pipe: 6-layer pipelined persistent kernel. Block = (layer, 16 cols).
// Global step g: layer l computes t = g - l; inputs h_{l-1}(t), h_l(t-1)
// were both published at step g-1 (flag barrier). Gates GEMM fused over
// K = {D_in | 512} + 512, split into 64KB k-window phases with async staging.
// 16 waves = 4 k-slices x 4 gates; acc[16] = 16 owned cols per gate.
// ===========================================================================
__global__ void __launch_bounds__(1024, 4) lstm_pipe(
    const float* __restrict__ x,
    const float* __restrict__ Wih0, const float* __restrict__ WihR,
    const float* __restrict__ Whh,
    const float* __restrict__ bih, const float* __restrict__ bhh,
    float* __restrict__ hbuf, unsigned* __restrict__ flags)
{
  __shared__ float lds[2 * SLABF + 64 * 65];   // 2 slabs + s_s = 149760 B
  float* const s_s   = lds + 2 * SLABF;
  float* const slab0 = lds;
  float* const slab1 = lds + SLABF;

  const int tid  = threadIdx.x;
  const int lane = tid & 63;                   // batch
  const int wl   = __builtin_amdgcn_readfirstlane(tid >> 6);
  const int ks   = wl & 3;                     // k-slice
  const int rq   = wl >> 2;                    // gate
  const int blk  = (int)blockIdx.x;
  const int l    = blk >> 5;                   // layer
  const int j0   = (blk & 31) * 16;            // owned cols j0..j0+15
  const int rowbase = rq * H + j0;

  const float* WihA = (l == 0) ? Wih0 : (WihR + (size_t)(l - 1) * G4 * H);
  const float* WhhA = Whh + (size_t)l * G4 * H;

  float biasr[16];
#pragma unroll
  for (int r = 0; r < 16; ++r)
    biasr[r] = bih[(size_t)l * G4 + rowbase + r] +
               bhh[(size_t)l * G4 + rowbase + r];

  // stage constants: h-slab [64 b][64 q] (64KB window), global [B][H]
  const int go0 = ((tid       ) >> 6) * H + ((tid       ) & 63) * 4;
  const int go1 = ((tid + 1024) >> 6) * H + ((tid + 1024) & 63) * 4;
  const int go2 = ((tid + 2048) >> 6) * H + ((tid + 2048) & 63) * 4;
  const int go3 = ((tid + 3072) >> 6) * H + ((tid + 3072) & 63) * 4;
  const int lo0 = (((tid       ) >> 6) * 65 + ((tid       ) & 63)) * 4;
  const int lo1 = (((tid + 1024) >> 6) * 65 + ((tid + 1024) & 63)) * 4;
  const int lo2 = (((tid + 2048) >> 6) * 65 + ((tid + 2048) & 63)) * 4;
  const int lo3 = (((tid + 3072) >> 6) * 65 + ((tid + 3072) & 63)) * 4;
  // x-stage constants: [64 b][32 q] (layer 0 only), global x[B][T][D0]
  const size_t xgo0 = (size_t)((tid       ) >> 5) * (T * D0) + ((tid       ) & 31) * 4;
  const size_t xgo1 = (size_t)((tid + 1024) >> 5) * (T * D0) + ((tid + 1024) & 31) * 4;
  const int xlo0 = (((tid       ) >> 5) * 33 + ((tid       ) & 31)) * 4;
  const int xlo1 = (((tid + 1024) >> 5) * 33 + ((tid + 1024) & 31)) * 4;

  const int pb = tid >> 4, pjj = tid & 15;     // pointwise: (batch, col)
  float creg = 0.f;                            // c-state lives in-register

  for (int g = 0; g < GTOT; ++g) {
    const int t = g - l;
    const bool active = (t >= 0) && (t < T);

    if (g > 0) {       // wait: all blocks finished step g-1
      if (tid < NBLK_P) {
        while (__hip_atomic_load(&flags[tid * FSTRIDE], __ATOMIC_RELAXED,
                                 __HIP_MEMORY_SCOPE_AGENT) < (unsigned)g)
          __builtin_amdgcn_s_sleep(1);
      }
      __syncthreads();
    }

    if (active) {
      float acc[16];
#pragma unroll
      for (int r = 0; r < 16; ++r) acc[r] = (ks == 0) ? biasr[r] : 0.f;

      const float* srcB = hbuf + ((size_t)l * 2 + ((t - 1) & 1)) * (B * H);

      if (l == 0) {
        { const float* xb = x + (size_t)t * D0;     // plain loads: x is const
          f32x4 v0 = *(const f32x4*)(xb + xgo0);
          f32x4 v1 = *(const f32x4*)(xb + xgo1);
          *(f32x4*)&slab0[xlo0] = v0;
          *(f32x4*)&slab0[xlo1] = v1; }
        __syncthreads();
        if (t > 0) {
          { f32x4 r0, r1, r2, r3;
            ISSUE4(srcB);
            gemm_ph<8, 33, D0>(slab0, WihA + (size_t)rowbase * D0, ks, lane, acc);
            WRITE4(slab1); }
          __syncthreads();
          { f32x4 r0, r1, r2, r3;
            ISSUE4(srcB + 256);
            gemm_ph<16, 65, H>(slab1, WhhA + (size_t)rowbase * H, ks, lane, acc);
            WRITE4(slab0); }
          __syncthreads();
          gemm_ph<16, 65, H>(slab0, WhhA + (size_t)rowbase * H + 256, ks, lane, acc);
          __syncthreads();
        } else {
          gemm_ph<8, 33, D0>(slab0, WihA + (size_t)rowbase * D0, ks, lane, acc);
          __syncthreads();
        }
      } else {
        const float* srcA = hbuf + ((size_t)(l - 1) * 2 + (t & 1)) * (B * H);
        { f32x4 r0, r1, r2, r3;
          ISSUE4(srcA);
          WRITE4(slab0); }
        __syncthreads();
        { f32x4 r0, r1, r2, r3;
          ISSUE4(srcA + 256);
          gemm_ph<16, 65, H>(slab0, WihA + (size_t)rowbase * H, ks, lane, acc);
          WRITE4(slab1); }
        __syncthreads();
        if (t > 0) {
          { f32x4 r0, r1, r2, r3;
            ISSUE4(srcB);
            gemm_ph<16, 65, H>(slab1, WihA + (size_t)rowbase * H + 256, ks, lane, acc);
            WRITE4(slab0); }
          __syncthreads();
          { f32x4 r0, r1, r2, r3;
            ISSUE4(srcB + 256);
            gemm_ph<16, 65, H>(slab0, WhhA + (size_t)rowbase * H, ks, lane, acc);
            WRITE4(slab1); }
          __syncthreads();
          gemm_ph<16, 65, H>(slab1, WhhA + (size_t)rowbase * H + 256, ks, lane, acc);
          __syncthreads();
        } else {
          gemm_ph<16, 65, H>(slab1, WihA + (size_t)rowbase * H + 256, ks, lane, acc);
          __syncthreads();
        }
      }

      // k-slice partials -> reduce (g_par aliases dead slabs)
      {
        float* g_par = lds;
#pragma unroll
        for (int r = 0; r < 16; ++r)
          g_par[ks * 4096 + (rq * 16 + r) * 64 + lane] = acc[r];
        __syncthreads();
#pragma unroll
        for (int i = 0; i < 4; ++i) {
          int o = tid + 1024 * i;               // o = rib*64 + b
          float sum = g_par[o] + g_par[4096 + o] +
                      g_par[8192 + o] + g_par[12288 + o];
          s_s[(o >> 6) * 65 + (o & 63)] = sum;
        }
      }
      __syncthreads();

      // pointwise + publish (sc write-through to coherence point)
      {
        float gi = s_s[( 0 + pjj) * 65 + pb];
        float gf = s_s[(16 + pjj) * 65 + pb];
        float gg = s_s[(32 + pjj) * 65 + pb];
        float go = s_s[(48 + pjj) * 65 + pb];
        float iv = 1.f / (1.f + expf(-gi));
        float fv = 1.f / (1.f + expf(-gf));
        float gv = tanhf(gg);
        float ov = 1.f / (1.f + expf(-go));
        creg = fv * creg + iv * gv;
        float hv = ov * tanhf(creg);
        float* hdst = hbuf + ((size_t)l * 2 + (t & 1)) * (B * H);
        __hip_atomic_store(&hdst[pb * H + j0 + pjj], hv,
                           __ATOMIC_RELAXED, __HIP_MEMORY_SCOPE_AGENT);
      }
      __syncthreads();   // drain publish stores before flagging
    }

    if (tid == 0)
      __hip_atomic_store(&flags[blk * FSTRIDE], (unsigned)(g + 1),
                         __ATOMIC_RELAXED, __HIP_MEMORY_SCOPE_AGENT);
  }
}

// ===========================================================================
// Final FC on h_5(T-1).
// ===========================================================================
__global__ void __launch_bounds__(640) fc_kernel(
    const float* __restrict__ h5, const float* __restrict__ w,
    const float* __restrict__ bias, float* __restrict__ out)
{
  int tid = threadIdx.x;
  if (tid >= 640) return;
  int b = tid / 10, o = tid - b * 10;
  const float* yr = h5 + (size_t)b * H;
  const float* wr = w + (size_t)o * H;
  float acc = bias[o];
  for (int k = 0; k < H; ++k) acc = fmaf(yr[k], wr[k], acc);
  out[b * 10 + o] = acc;
}

extern "C" void kernel_launch(void* const* d_in, const int* in_sizes, int n_in,
                              void* d_out, int out_size, void* d_ws,
                              size_t ws_size, hipStream_t stream)
{
  const float* x    = (const float*)d_in[0];
  const float* Wih0 = (const float*)d_in[1];
  const float* WihR = (const float*)d_in[2];
  const float* Whh  = (const float*)d_in[3];
  const float* bih  = (const float*)d_in[4];
  const float* bhh  = (const float*)d_in[5];
  const float* fcw  = (const float*)d_in[6];
  const float* fcb  = (const float*)d_in[7];
  float* out = (float*)d_out;

  // ws: [0,16K) flags; hbuf[6 layers][2 slots][B][H] f32 (1.5 MB ring)
  unsigned* flags = (unsigned*)d_ws;
  float* hbuf = (float*)((char*)d_ws + 16384);

  hipMemsetAsync(d_ws, 0, 16384, stream);   // flags monotonic within a call

  lstm_pipe<<<NBLK_P, 1024, 0, stream>>>(x, Wih0, WihR, Whh, bih, bhh,
                                         hbuf, flags);
  // h_5(T-1) is in slot (T-1)&1 = 1 of layer 5
  fc_kernel<<<1, 640, 0, stream>>>(hbuf + (size_t)(5 * 2 + 1) * B * H,
                                   fcw, fcb, out);
}

// Round 10
// 7731.854 us; speedup vs baseline: 2.8626x; 2.2118x over previous
//
#include <hip/hip_runtime.h>

#define B 64
#define T 256
#define H 512
#define G4 2048
#define D0 128
#define NL 6
#define NBLK_P 192            // 6 layers x 32 col-groups, 1 block/CU
#define GTOT (T + NL - 1)     // 261 global pipeline steps
#define FSTRIDE 16            // u32 stride between per-block flags (64B)
#define KW 128                // k-window (f16) staged per phase

typedef float f32x4 __attribute__((ext_vector_type(4)));
typedef _Float16 h16x2 __attribute__((ext_vector_type(2)));
typedef _Float16 h16x8 __attribute__((ext_vector_type(8)));

// v_dot2_f32_f16: 2 f16 MACs, f32 accumulate. Guarded: __has_builtin on
// ROCm>=7 clang respects target features, so if gfx950 lacked dot2 this
// still compiles via the cvt+fma fallback (slower, same numerics).
#if __has_builtin(__builtin_amdgcn_fdot2)
#define FDOT2(a, b, c) __builtin_amdgcn_fdot2((a), (b), (c), false)
#else
#define FDOT2(a, b, c) fmaf((float)(a).x, (float)(b).x, \
                       fmaf((float)(a).y, (float)(b).y, (c)))
#endif

__device__ __forceinline__ float dot8(h16x8 w8, h16x8 h8, float acc) {
  h16x2 a, b;
  a.x = w8[0]; a.y = w8[1]; b.x = h8[0]; b.y = h8[1]; acc = FDOT2(a, b, acc);
  a.x = w8[2]; a.y = w8[3]; b.x = h8[2]; b.y = h8[3]; acc = FDOT2(a, b, acc);
  a.x = w8[4]; a.y = w8[5]; b.x = h8[4]; b.y = h8[5]; acc = FDOT2(a, b, acc);
  a.x = w8[6]; a.y = w8[7]; b.x = h8[6]; b.y = h8[7]; acc = FDOT2(a, b, acc);
  return acc;
}

// Coherent 16B load (proven round 9): bypasses stale per-XCD L2 for the
// reused h ring slots.
#define CLOAD(dst, p) \
  asm volatile("global_load_dwordx4 %0, %1, off sc0 sc1" : "=&v"(dst) : "v"(p))
#define VMWAIT do { asm volatile("s_waitcnt vmcnt(0)" ::: "memory"); \
                    __builtin_amdgcn_sched_barrier(0); } while (0)

// ===========================================================================
// lstm_pipe v2 — WEIGHT-STATIONARY. Round-9's pipeline skeleton (barrier,
// publish, pointwise) unchanged; the weight stream (12.7 GB FETCH, the 66us
// step) is replaced by a one-time fp16 W slice in LDS (128 KB/block).
//  * 16 waves x 4 gate-rows, full K per wave (no k-split -> no reduce buf).
//  * W read as wave-uniform broadcast ds_read_b128 (8 f16 -> 4 fdot2).
//  * h staged per 128-k window: CLOAD prefetch -> cvt f16 -> LDS (XOR-swz
//    16B units, ~2-way banks). Windows never straddle inA/inB (l0: 128|512,
//    else 512|512).
//  * s_s (gate sums, f32 [64][64]) ALIASES h_win — both 16 KB, h_win dead
//    at reduce time. LDS total 144 KB.
// ===========================================================================
__global__ void __launch_bounds__(1024, 4) lstm_pipe(
    const float* __restrict__ x,
    const float* __restrict__ Wih0, const float* __restrict__ WihR,
    const float* __restrict__ Whh,
    const float* __restrict__ bih, const float* __restrict__ bhh,
    float* __restrict__ hbuf, unsigned* __restrict__ flags)
{
  __shared__ unsigned short w_lds[64][1024];   // fp16 W slice, 128 KB
  __shared__ unsigned short h_win[64][KW];     // fp16 h window, 16 KB
  float* const s_s = (float*)&h_win[0][0];     // [64 ri][64 b] f32, aliased

  const int tid  = threadIdx.x;
  const int lane = tid & 63;                   // batch
  const int wl   = __builtin_amdgcn_readfirstlane(tid >> 6);
  const int blk  = (int)blockIdx.x;
  const int l    = blk >> 5;                   // layer
  const int j0   = (blk & 31) * 16;            // owned cols j0..j0+15
  const int Kin  = (l == 0) ? D0 : H;
  const int NWIN = (Kin + H) / KW;             // 5 or 8
  const int WIN_A = Kin / KW;                  // inA windows: 1 or 4

  const float* WihA = (l == 0) ? Wih0 : (WihR + (size_t)(l - 1) * G4 * H);
  const float* WhhA = Whh + (size_t)l * G4 * H;

  // ---- one-time W prologue: cat [Wih | Whh] rows -> w_lds fp16 (RTN) ----
  // local row ri: gate = ri>>4, col = j0 + (ri&15)
  for (int p = tid; p < 64 * (Kin / 2); p += 1024) {
    int ri = p / (Kin / 2), kp = (p % (Kin / 2)) * 2;
    int grow = (ri >> 4) * H + j0 + (ri & 15);
    const float* src = WihA + (size_t)grow * Kin + kp;
    h16x2 v; v.x = (_Float16)src[0]; v.y = (_Float16)src[1];
    *(h16x2*)&w_lds[ri][kp] = v;
  }
  for (int p = tid; p < 64 * (H / 2); p += 1024) {
    int ri = p / (H / 2), kp = (p % (H / 2)) * 2;
    int grow = (ri >> 4) * H + j0 + (ri & 15);
    const float* src = WhhA + (size_t)grow * H + kp;
    h16x2 v; v.x = (_Float16)src[0]; v.y = (_Float16)src[1];
    *(h16x2*)&w_lds[ri][Kin + kp] = v;
  }

  // wave's 4 rows + bias (wave-uniform)
  const int r0 = wl * 4;
  float biasr[4];
#pragma unroll
  for (int r = 0; r < 4; ++r) {
    int ri = r0 + r;
    int grow = (ri >> 4) * H + j0 + (ri & 15);
    biasr[r] = bih[(size_t)l * G4 + grow] + bhh[(size_t)l * G4 + grow];
  }

  // window-stage mapping: thread -> (batch sb, 16B unit su), XOR-swizzled
  const int sb = tid >> 4, su = tid & 15;
  const int swz = (su ^ (sb & 7)) * 8;         // f16 offset within row

  const int pb = tid >> 4, pcj = tid & 15;     // pointwise (batch, col)
  float creg = 0.f;

  __syncthreads();   // W resident

  for (int g = 0; g < GTOT; ++g) {
    const int t = g - l;
    const bool active = (t >= 0) && (t < T);

    if (g > 0) {     // wait: all blocks finished step g-1 (proven flag array)
      if (tid < NBLK_P) {
        while (__hip_atomic_load(&flags[tid * FSTRIDE], __ATOMIC_RELAXED,
                                 __HIP_MEMORY_SCOPE_AGENT) < (unsigned)g)
          __builtin_amdgcn_s_sleep(1);
      }
      __syncthreads();
    }

    if (active) {
      const int nwin = (t == 0) ? WIN_A : NWIN;   // t=0: no h(t-1) windows
      const float* inA = (l == 0) ? (x + (size_t)t * D0)
                                  : (hbuf + ((size_t)(l - 1) * 2 + (t & 1)) * (B * H));
      const float* inB = hbuf + ((size_t)l * 2 + ((t - 1) & 1)) * (B * H);

      float acc0 = biasr[0], acc1 = biasr[1], acc2 = biasr[2], acc3 = biasr[3];

      // prefetch window 0 (always inA)
      f32x4 pr0, pr1;
      if (l == 0) {
        const float* sp = inA + (size_t)sb * (T * D0) + su * 8;
        pr0 = *(const f32x4*)sp; pr1 = *(const f32x4*)(sp + 4);
      } else {
        const float* sp = inA + (size_t)sb * H + su * 8;
        CLOAD(pr0, sp); CLOAD(pr1, sp + 4);
      }

      for (int win = 0; win < nwin; ++win) {
        // commit prefetched window to LDS as fp16 (swizzled b128)
        VMWAIT;
        {
          h16x8 hv;
          hv[0] = (_Float16)pr0.x; hv[1] = (_Float16)pr0.y;
          hv[2] = (_Float16)pr0.z; hv[3] = (_Float16)pr0.w;
          hv[4] = (_Float16)pr1.x; hv[5] = (_Float16)pr1.y;
          hv[6] = (_Float16)pr1.z; hv[7] = (_Float16)pr1.w;
          *(h16x8*)&h_win[sb][swz] = hv;
        }
        __syncthreads();

        // prefetch next window during compute (T14 async split)
        if (win + 1 < nwin) {
          int k0n = (win + 1) * KW;
          const float* sp = (k0n < Kin)
              ? inA + (size_t)sb * H + k0n + su * 8            // only l>0
              : inB + (size_t)sb * H + (k0n - Kin) + su * 8;
          CLOAD(pr0, sp); CLOAD(pr1, sp + 4);
        }

        // compute: wave's 4 rows x this 128-k window
        const int kw0 = win * KW;
#pragma unroll 4
        for (int q = 0; q < 16; ++q) {
          h16x8 h8 = *(const h16x8*)&h_win[lane][(q ^ (lane & 7)) * 8];
          h16x8 w80 = *(const h16x8*)&w_lds[r0 + 0][kw0 + q * 8];  // broadcast
          h16x8 w81 = *(const h16x8*)&w_lds[r0 + 1][kw0 + q * 8];
          h16x8 w82 = *(const h16x8*)&w_lds[r0 + 2][kw0 + q * 8];
          h16x8 w83 = *(const h16x8*)&w_lds[r0 + 3][kw0 + q * 8];
          acc0 = dot8(w80, h8, acc0);
          acc1 = dot8(w81, h8, acc1);
          acc2 = dot8(w82, h8, acc2);
          acc3 = dot8(w83, h8, acc3);
        }
        __syncthreads();   // h_win reuse (next window / s_s alias)
      }

      // gate sums -> s_s (aliases h_win; all window compute done)
      s_s[(r0 + 0) * 64 + lane] = acc0;
      s_s[(r0 + 1) * 64 + lane] = acc1;
      s_s[(r0 + 2) * 64 + lane] = acc2;
      s_s[(r0 + 3) * 64 + lane] = acc3;
      __syncthreads();

      // pointwise (all 1024 threads: 64 b x 16 cols) + publish
      {
        float gi = s_s[( 0 + pcj) * 64 + pb];
        float gf = s_s[(16 + pcj) * 64 + pb];
        float gg = s_s[(32 + pcj) * 64 + pb];
        float go = s_s[(48 + pcj) * 64 + pb];
        float iv = 1.f / (1.f + expf(-gi));
        float fv = 1.f / (1.f + expf(-gf));
        float gv = tanhf(gg);
        float ov = 1.f / (1.f + expf(-go));
        creg = fv * creg + iv * gv;
        float hv = ov * tanhf(creg);
        float* hdst = hbuf + ((size_t)l * 2 + (t & 1)) * (B * H);
        __hip_atomic_store(&hdst[pb * H + j0 + pcj], hv,
                           __ATOMIC_RELAXED, __HIP_MEMORY_SCOPE_AGENT);
      }
      __syncthreads();   // drain publish stores before flagging
    }

    if (tid == 0)
      __hip_atomic_store(&flags[blk * FSTRIDE], (unsigned)(g + 1),
                         __ATOMIC_RELAXED, __HIP_MEMORY_SCOPE_AGENT);
  }
}

// ===========================================================================
// Final FC on h_5(T-1)  (slot (T-1)&1 = 1 of layer 5)
// ===========================================================================
__global__ void __launch_bounds__(640) fc_kernel(
    const float* __restrict__ h5, const float* __restrict__ w,
    const float* __restrict__ bias, float* __restrict__ out)
{
  int tid = threadIdx.x;
  if (tid >= 640) return;
  int b = tid / 10, o = tid - b * 10;
  const float* yr = h5 + (size_t)b * H;
  const float* wr = w + (size_t)o * H;
  float acc = bias[o];
  for (int k = 0; k < H; ++k) acc = fmaf(yr[k], wr[k], acc);
  out[b * 10 + o] = acc;
}

extern "C" void kernel_launch(void* const* d_in, const int* in_sizes, int n_in,
                              void* d_out, int out_size, void* d_ws,
                              size_t ws_size, hipStream_t stream)
{
  const float* x    = (const float*)d_in[0];
  const float* Wih0 = (const float*)d_in[1];
  const float* WihR = (const float*)d_in[2];
  const float* Whh  = (const float*)d_in[3];
  const float* bih  = (const float*)d_in[4];
  const float* bhh  = (const float*)d_in[5];
  const float* fcw  = (const float*)d_in[6];
  const float* fcb  = (const float*)d_in[7];
  float* out = (float*)d_out;

  // ws: [0,16K) flags; hbuf[6 layers][2 slots][B][H] f32 (1.5 MB ring)
  unsigned* flags = (unsigned*)d_ws;
  float* hbuf = (float*)((char*)d_ws + 16384);

  hipMemsetAsync(d_ws, 0, 16384, stream);   // flags monotonic within a call

  lstm_pipe<<<NBLK_P, 1024, 0, stream>>>(x, Wih0, WihR, Whh, bih, bhh,
                                         hbuf, flags);
  fc_kernel<<<1, 640, 0, stream>>>(hbuf + (size_t)(5 * 2 + 1) * B * H,
                                   fcw, fcb, out);
}

// Round 11
// 2354.317 us; speedup vs baseline: 9.4010x; 3.2841x over previous
//
#include <hip/hip_runtime.h>

#define B 64
#define T 256
#define H 512
#define G4 2048
#define D0 128
#define NL 6
#define NBLK_P 192            // 6 layers x 32 col-groups, 1 block/CU
#define GTOT (T + NL - 1)     // 261 global pipeline steps
#define FSTRIDE 16            // u32 stride between per-block flags (64B)
#define WSTRIDE 1032          // w_lds row stride, f16 units (1024 + 8 pad)
#define HSTRIDE 136           // h_win row stride, f16 units (128 + 8 pad)
#define SSTRIDE 68            // s_s row stride, f32 units (64 + 4 pad)

typedef float f32x4 __attribute__((ext_vector_type(4)));
typedef _Float16 h16x2 __attribute__((ext_vector_type(2)));
typedef _Float16 h16x8 __attribute__((ext_vector_type(8)));

// Coherent 16B load (proven r9/r10): bypasses stale per-XCD L2 for the
// h ring slots whose addresses are reused every 2 steps.
#define CLOAD(dst, p) \
  asm volatile("global_load_dwordx4 %0, %1, off sc0 sc1" : "=&v"(dst) : "v"(p))
#define VMWAIT do { asm volatile("s_waitcnt vmcnt(0)" ::: "memory"); \
                    __builtin_amdgcn_sched_barrier(0); } while (0)

// ===========================================================================
// lstm_pipe v3 — MFMA. Round-10 skeleton (pipeline, flag barrier, publish,
// pointwise, fp16-W-stationary LDS) unchanged; the fdot2 GEMM (471M bank-
// conflict cycles + 40% VALUBusy) is replaced by f16 MFMA:
//  * 16 waves = 4 row-tiles x 4 batch-tiles; wave owns one 16x16 C tile,
//    full K. 32 MFMA + 64 frag-reads per wave per step (was 2048 fdot2).
//  * A-frag: W[rt*16+(lane&15)][(lane>>4)*8+e]  (w_lds row-major, pad 1032)
//    B-frag: h_win[bt*16+(lane&15)][(lane>>4)*8+e] ([batch][k], pad 136)
//    C/D:    row=(lane>>4)*4+reg, col=lane&15     (HW-verified m89 mapping)
//  * padded strides (2064B=16 mod 128, 272B, 272B) -> all LDS ops <=2-way.
//  * h staged in 128-k windows, single buffer, CLOAD reg-prefetch (r10).
//  * LDS: W 132096 + h_win 17408 (s_s f32[64][68] aliases it) = 149504 B.
// ===========================================================================
__global__ void __launch_bounds__(1024, 4) lstm_pipe(
    const float* __restrict__ x,
    const float* __restrict__ Wih0, const float* __restrict__ WihR,
    const float* __restrict__ Whh,
    const float* __restrict__ bih, const float* __restrict__ bhh,
    float* __restrict__ hbuf, unsigned* __restrict__ flags)
{
  __shared__ unsigned short w_lds[64 * WSTRIDE];   // 132096 B fp16 W slice
  __shared__ unsigned short h_win[64 * HSTRIDE];   // 17408 B fp16 h window
  float* const s_s = (float*)h_win;                // [64][68] f32, aliased

  const int tid  = threadIdx.x;
  const int lane = tid & 63;
  const int wl   = __builtin_amdgcn_readfirstlane(tid >> 6);
  const int rt   = wl >> 2;                    // row-tile (= gate)
  const int bt   = wl & 3;                     // batch-tile
  const int blk  = (int)blockIdx.x;
  const int l    = blk >> 5;                   // layer
  const int j0   = (blk & 31) * 16;            // owned cols j0..j0+15
  const int Kin  = (l == 0) ? D0 : H;
  const int WIN_A = Kin >> 7;                  // inA windows: 1 or 4
  const int NWIN  = WIN_A + 4;                 // + 4 inB windows

  const float* WihA = (l == 0) ? Wih0 : (WihR + (size_t)(l - 1) * G4 * H);
  const float* WhhA = Whh + (size_t)l * G4 * H;

  // ---- one-time W prologue: cat [Wih | Whh] rows -> w_lds fp16 ----
  // local row ri: gate = ri>>4, col = j0 + (ri&15)   (same map as r10)
  {
    const int khalf  = Kin >> 1;
    const int kshift = (l == 0) ? 6 : 8;
    for (int p = tid; p < 64 * khalf; p += 1024) {
      int ri = p >> kshift, kp = (p & (khalf - 1)) * 2;
      int grow = (ri >> 4) * H + j0 + (ri & 15);
      const float* src = WihA + (size_t)grow * Kin + kp;
      h16x2 v; v.x = (_Float16)src[0]; v.y = (_Float16)src[1];
      *(h16x2*)&w_lds[ri * WSTRIDE + kp] = v;
    }
    for (int p = tid; p < 64 * 256; p += 1024) {
      int ri = p >> 8, kp = (p & 255) * 2;
      int grow = (ri >> 4) * H + j0 + (ri & 15);
      const float* src = WhhA + (size_t)grow * H + kp;
      h16x2 v; v.x = (_Float16)src[0]; v.y = (_Float16)src[1];
      *(h16x2*)&w_lds[ri * WSTRIDE + Kin + kp] = v;
    }
  }

  // per-lane fragment offsets (f16 units)
  const int aOff = (rt * 16 + (lane & 15)) * WSTRIDE + ((lane >> 4) * 8);
  const int bOff = (bt * 16 + (lane & 15)) * HSTRIDE + ((lane >> 4) * 8);
  const int eRow = rt * 16 + (lane >> 4) * 4;      // epilogue C rows
  const int eCol = bt * 16 + (lane & 15);

  // per-step accumulator init = bias for the 4 C rows this lane owns
  f32x4 biasv;
#pragma unroll
  for (int r = 0; r < 4; ++r) {
    int grow = rt * H + j0 + ((lane >> 4) * 4 + r);
    biasv[r] = bih[(size_t)l * G4 + grow] + bhh[(size_t)l * G4 + grow];
  }

  // stage mapping: thread -> (batch sb, 8-f16 unit su)
  const int sb = tid >> 4, su = tid & 15;
  const int pb = tid >> 4, pcj = tid & 15;     // pointwise (batch, col)
  float creg = 0.f;

  __syncthreads();   // W resident

  for (int g = 0; g < GTOT; ++g) {
    const int t = g - l;
    const bool active = (t >= 0) && (t < T);

    if (g > 0) {     // wait: all blocks finished step g-1 (proven flag array)
      if (tid < NBLK_P) {
        while (__hip_atomic_load(&flags[tid * FSTRIDE], __ATOMIC_RELAXED,
                                 __HIP_MEMORY_SCOPE_AGENT) < (unsigned)g)
          __builtin_amdgcn_s_sleep(1);
      }
      __syncthreads();
    }

    if (active) {
      const int nwin = (t == 0) ? WIN_A : NWIN;
      const float* inA = (l == 0) ? (const float*)0
          : (hbuf + ((size_t)(l - 1) * 2 + (t & 1)) * (B * H));
      const float* inB = hbuf + ((size_t)l * 2 + ((t - 1) & 1)) * (B * H);

      f32x4 acc = biasv;
      f32x4 pr0, pr1;

      // issue window 0 (always inA-side)
      if (l == 0) {
        const float* sp = x + (size_t)sb * (T * D0) + (size_t)t * D0 + su * 8;
        pr0 = *(const f32x4*)sp; pr1 = *(const f32x4*)(sp + 4);
      } else {
        const float* sp = inA + (size_t)sb * H + su * 8;
        CLOAD(pr0, sp); CLOAD(pr1, sp + 4);
      }

      for (int win = 0; win < nwin; ++win) {
        // commit prefetched 128-k window to LDS as fp16
        VMWAIT;
        {
          h16x8 hv;
          hv[0] = (_Float16)pr0.x; hv[1] = (_Float16)pr0.y;
          hv[2] = (_Float16)pr0.z; hv[3] = (_Float16)pr0.w;
          hv[4] = (_Float16)pr1.x; hv[5] = (_Float16)pr1.y;
          hv[6] = (_Float16)pr1.z; hv[7] = (_Float16)pr1.w;
          *(h16x8*)&h_win[sb * HSTRIDE + su * 8] = hv;
        }
        __syncthreads();

        // prefetch next window during compute (r10 async split)
        if (win + 1 < nwin) {
          int wn = win + 1;
          const float* sp = (wn < WIN_A)
              ? inA + (size_t)sb * H + wn * 128 + su * 8
              : inB + (size_t)sb * H + (wn - WIN_A) * 128 + su * 8;
          CLOAD(pr0, sp); CLOAD(pr1, sp + 4);
        }

        // 4 MFMA k-steps over this window
        const unsigned short* wbase = &w_lds[aOff + win * 128];
#pragma unroll
        for (int kb = 0; kb < 4; ++kb) {
          h16x8 a8 = *(const h16x8*)(wbase + kb * 32);
          h16x8 b8 = *(const h16x8*)&h_win[bOff + kb * 32];
          acc = __builtin_amdgcn_mfma_f32_16x16x32_f16(a8, b8, acc, 0, 0, 0);
        }
        __syncthreads();   // h_win reuse (next window / s_s alias)
      }

      // epilogue: C frag -> s_s (aliases h_win; all windows done)
#pragma unroll
      for (int r = 0; r < 4; ++r)
        s_s[(eRow + r) * SSTRIDE + eCol] = acc[r];
      __syncthreads();

      // pointwise (64 b x 16 cols) + publish
      {
        float gi = s_s[( 0 + pcj) * SSTRIDE + pb];
        float gf = s_s[(16 + pcj) * SSTRIDE + pb];
        float gg = s_s[(32 + pcj) * SSTRIDE + pb];
        float go = s_s[(48 + pcj) * SSTRIDE + pb];
        float iv = 1.f / (1.f + expf(-gi));
        float fv = 1.f / (1.f + expf(-gf));
        float gv = tanhf(gg);
        float ov = 1.f / (1.f + expf(-go));
        creg = fv * creg + iv * gv;
        float hv = ov * tanhf(creg);
        float* hdst = hbuf + ((size_t)l * 2 + (t & 1)) * (B * H);
        __hip_atomic_store(&hdst[pb * H + j0 + pcj], hv,
                           __ATOMIC_RELAXED, __HIP_MEMORY_SCOPE_AGENT);
      }
      __syncthreads();   // drain publish stores before flagging
    }

    if (tid == 0)
      __hip_atomic_store(&flags[blk * FSTRIDE], (unsigned)(g + 1),
                         __ATOMIC_RELAXED, __HIP_MEMORY_SCOPE_AGENT);
  }
}

// ===========================================================================
// Final FC on h_5(T-1)  (slot (T-1)&1 = 1 of layer 5)
// ===========================================================================
__global__ void __launch_bounds__(640) fc_kernel(
    const float* __restrict__ h5, const float* __restrict__ w,
    const float* __restrict__ bias, float* __restrict__ out)
{
  int tid = threadIdx.x;
  if (tid >= 640) return;
  int b = tid / 10, o = tid - b * 10;
  const float* yr = h5 + (size_t)b * H;
  const float* wr = w + (size_t)o * H;
  float acc = bias[o];
  for (int k = 0; k < H; ++k) acc = fmaf(yr[k], wr[k], acc);
  out[b * 10 + o] = acc;
}

extern "C" void kernel_launch(void* const* d_in, const int* in_sizes, int n_in,
                              void* d_out, int out_size, void* d_ws,
                              size_t ws_size, hipStream_t stream)
{
  const float* x    = (const float*)d_in[0];
  const float* Wih0 = (const float*)d_in[1];
  const float* WihR = (const float*)d_in[2];
  const float* Whh  = (const float*)d_in[3];
  const float* bih  = (const float*)d_in[4];
  const float* bhh  = (const float*)d_in[5];
  const float* fcw  = (const float*)d_in[6];
  const float* fcb  = (const float*)d_in[7];
  float* out = (float*)d_out;

  // ws: [0,16K) flags; hbuf[6 layers][2 slots][B][H] f32 (1.5 MB ring)
  unsigned* flags = (unsigned*)d_ws;
  float* hbuf = (float*)((char*)d_ws + 16384);

  hipMemsetAsync(d_ws, 0, 16384, stream);   // flags monotonic within a call

  lstm_pipe<<<NBLK_P, 1024, 0, stream>>>(x, Wih0, WihR, Whh, bih, bhh,
                                         hbuf, flags);
  fc_kernel<<<1, 640, 0, stream>>>(hbuf + (size_t)(5 * 2 + 1) * B * H,
                                   fcw, fcb, out);
}

// Round 12
// 1599.783 us; speedup vs baseline: 13.8350x; 1.4716x over previous
//
#include <hip/hip_runtime.h>

#define B 64
#define T 256
#define H 512
#define G4 2048
#define D0 128
#define NL 6
#define NBLK_P 192            // 6 layers x 32 col-groups, 1 block/CU
#define GTOT (T + NL - 1)     // 261 global pipeline steps
#define FSTRIDE 16            // u32 stride between per-block flags (64B)
#define HSTR 1032             // h_s row stride, f16 units (1024 + 8 pad)
#define GSTR 36               // g_par row-dim stride, f32 (32 + 4)

typedef float f32x4 __attribute__((ext_vector_type(4)));
typedef float f32x16 __attribute__((ext_vector_type(16)));
typedef _Float16 h16x8 __attribute__((ext_vector_type(8)));

// Coherent 16B load (proven r9-r11): bypasses stale per-XCD L2 for ring
// slots whose addresses are reused every 2 steps.
#define CLOAD(dst, p) \
  asm volatile("global_load_dwordx4 %0, %1, off sc0 sc1" : "=&v"(dst) : "v"(p))
#define VMWAIT do { asm volatile("s_waitcnt vmcnt(0)" ::: "memory"); \
                    __builtin_amdgcn_sched_barrier(0); } while (0)

// ===========================================================================
// lstm_pipe v4 — W-in-REGISTERS + 32x32x16 MFMA + f16 h-ring.
//  * 16 waves = 4 C-tiles(32x32: rt,bt) x 4 k-slices(256). A-frags (W) live
//    in 64 VGPRs/lane, loaded ONCE -> zero per-step LDS traffic for W
//    (r11 spent ~half its step re-reading W fragments from LDS).
//  * A: row=lane&31, k=(lane>>5)*8+e (analog of the r11-verified 16x16 map);
//    C/D (m74-verified): col=lane&31, row=(reg&3)+8(reg>>2)+4(lane>>5).
//  * h ring is f16: publish cvt once -> staging is a pure 16B copy (no cvt),
//    24 MB/step from L3 instead of 48. h_s [64][1032] f16; stage-write slot
//    (sb+u)%8 and B-read slot (row+2m+hi)%8 both uniform -> conflict-free.
//  * k-slice reduce via g_par f32[4ks][4tile][32col][36] (73.7 KB), ALIASES
//    h_s (dead after MFMA phase; extra __syncthreads guards the overlap).
//  * l=0 (K=640): wave-uniform skip of MFMAs with k>=KTOT; t=0 stages zeros
//    for the h(t-1) region (= exact h(-1)=0 semantics).
//  * FC precision: (l=5,t=T-1) also writes f32 h to h5buf.
//  Pipeline skeleton (flags, sc1 publish, pointwise c-in-reg): r9-11 proven.
// ===========================================================================
__global__ void __launch_bounds__(1024, 4) lstm_pipe(
    const float* __restrict__ x,
    const float* __restrict__ Wih0, const float* __restrict__ WihR,
    const float* __restrict__ Whh,
    const float* __restrict__ bih, const float* __restrict__ bhh,
    unsigned short* __restrict__ ring, float* __restrict__ h5,
    unsigned* __restrict__ flags)
{
  __shared__ unsigned short h_s[64 * HSTR];     // 132096 B
  float* const g_par = (float*)h_s;             // 73728 B, aliased

  const int tid  = threadIdx.x;
  const int lane = tid & 63;
  const int wl   = __builtin_amdgcn_readfirstlane(tid >> 6);
  const int ks   = wl & 3;                  // k-slice (256 k)
  const int rt   = (wl >> 2) >> 1;          // C row-tile (32 rows)
  const int bt   = (wl >> 2) & 1;           // C batch-tile (32 cols)
  const int blk  = (int)blockIdx.x;
  const int l    = blk >> 5;                // layer
  const int j0   = (blk & 31) * 16;         // owned cols j0..j0+15
  const int Kin  = (l == 0) ? D0 : H;
  const int KTOT = Kin + 512;               // 640 or 1024
  const int NU   = KTOT >> 3;               // 16B units per batch row

  const float* WihA = (l == 0) ? Wih0 : (WihR + (size_t)(l - 1) * G4 * H);
  const float* WhhA = Whh + (size_t)l * G4 * H;

  // ---- one-time: W slice -> A-fragments in registers (fp16) ----
  h16x8 a[16];
  {
    const int ri   = rt * 32 + (lane & 31);           // local row 0..63
    const int grow = (ri >> 4) * H + j0 + (ri & 15);  // gate*H + col
    const float* wihRow = WihA + (size_t)grow * Kin;
    const float* whhRow = WhhA + (size_t)grow * H;
    const int klane = (lane >> 5) * 8;
#pragma unroll
    for (int m = 0; m < 16; ++m) {
      int kb = ks * 256 + m * 16;
      h16x8 f = {};
      if (kb < KTOT) {
        const float* src = (kb < Kin) ? (wihRow + kb + klane)
                                      : (whhRow + (kb - Kin) + klane);
        f32x4 v0 = *(const f32x4*)src;
        f32x4 v1 = *(const f32x4*)(src + 4);
        f[0] = (_Float16)v0.x; f[1] = (_Float16)v0.y;
        f[2] = (_Float16)v0.z; f[3] = (_Float16)v0.w;
        f[4] = (_Float16)v1.x; f[5] = (_Float16)v1.y;
        f[6] = (_Float16)v1.z; f[7] = (_Float16)v1.w;
      }
      a[m] = f;
    }
  }

  // pointwise ownership + bias (bias added at reduce time; reassoc ~1e-6)
  const int pb = tid >> 4, pcj = tid & 15;
  float bias4[4];
#pragma unroll
  for (int gi = 0; gi < 4; ++gi) {
    int grow = gi * H + j0 + pcj;
    bias4[gi] = bih[(size_t)l * G4 + grow] + bhh[(size_t)l * G4 + grow];
  }

  // stage mapping: thread -> (batch row sb, base unit u0)
  const int sb = tid >> 4, u0 = tid & 15;
  float creg = 0.f;

  for (int g = 0; g < GTOT; ++g) {
    const int t = g - l;
    const bool active = (t >= 0) && (t < T);

    if (g > 0) {   // wait: all blocks finished step g-1 (proven flag array)
      if (tid < NBLK_P) {
        while (__hip_atomic_load(&flags[tid * FSTRIDE], __ATOMIC_RELAXED,
                                 __HIP_MEMORY_SCOPE_AGENT) < (unsigned)g)
          __builtin_amdgcn_s_sleep(1);
      }
      __syncthreads();
    }

    if (active) {
      // ---- stage h_cat = [inA | inB] as f16 into h_s ----
      const unsigned short* rowA = ring +
          (size_t)((l - 1) * 2 + (t & 1)) * (B * H) + sb * H;   // l>0 only
      const unsigned short* rowB = ring +
          (size_t)(l * 2 + ((t - 1) & 1)) * (B * H) + sb * H;
      unsigned short* dst = &h_s[sb * HSTR];

      if (l == 0) {    // x region: units 0..15, f32 -> f16 cvt
        const float* xr = x + ((size_t)sb * T + t) * D0 + u0 * 8;
        f32x4 v0 = *(const f32x4*)xr, v1 = *(const f32x4*)(xr + 4);
        h16x8 hv;
        hv[0] = (_Float16)v0.x; hv[1] = (_Float16)v0.y;
        hv[2] = (_Float16)v0.z; hv[3] = (_Float16)v0.w;
        hv[4] = (_Float16)v1.x; hv[5] = (_Float16)v1.y;
        hv[6] = (_Float16)v1.z; hv[7] = (_Float16)v1.w;
        *(h16x8*)&dst[u0 * 8] = hv;
      }
      const int i0 = (l == 0) ? 1 : 0;
#pragma unroll
      for (int half = 0; half < 2; ++half) {
        f32x4 rr[4];
#pragma unroll
        for (int jj = 0; jj < 4; ++jj) {
          int i = half * 4 + jj;
          int u = u0 + 16 * i;
          if (i >= i0 && u < NU) {
            int k16 = u * 8;
            if (k16 >= Kin) {
              if (t == 0) { f32x4 z = {0.f, 0.f, 0.f, 0.f}; rr[jj] = z; }
              else        CLOAD(rr[jj], rowB + (k16 - Kin));
            } else {
              CLOAD(rr[jj], rowA + k16);
            }
          }
        }
        VMWAIT;
#pragma unroll
        for (int jj = 0; jj < 4; ++jj) {
          int i = half * 4 + jj;
          int u = u0 + 16 * i;
          if (i >= i0 && u < NU)
            *(f32x4*)&dst[u * 8] = rr[jj];
        }
      }
      __syncthreads();

      // ---- 16 MFMAs: wave's (rt,bt) tile x its 256-k slice ----
      f32x16 accv = {};
      const unsigned short* brow =
          &h_s[(bt * 32 + (lane & 31)) * HSTR + ks * 256 + (lane >> 5) * 8];
#pragma unroll
      for (int m = 0; m < 16; ++m) {
        if (ks * 256 + m * 16 < KTOT) {        // wave-uniform skip (l=0 tail)
          h16x8 b8 = *(const h16x8*)(brow + m * 16);
          accv = __builtin_amdgcn_mfma_f32_32x32x16_f16(a[m], b8, accv, 0, 0, 0);
        }
      }
      __syncthreads();   // all B-reads done -> g_par may alias h_s

      // ---- k-slice partials -> g_par (b128, slot-uniform) ----
      {
        float* gp = g_par +
            (size_t)((ks * 4 + (rt * 2 + bt)) * 32 + (lane & 31)) * GSTR +
            4 * (lane >> 5);
#pragma unroll
        for (int q = 0; q < 4; ++q) {
          f32x4 tv;
          tv.x = accv[4 * q];     tv.y = accv[4 * q + 1];
          tv.z = accv[4 * q + 2]; tv.w = accv[4 * q + 3];
          *(f32x4*)&gp[8 * q] = tv;    // rows 8q + 4*(lane>>5) + 0..3
        }
      }
      __syncthreads();

      // ---- reduce + bias + pointwise + publish ----
      {
        float gt[4];
#pragma unroll
        for (int gi = 0; gi < 4; ++gi) {
          int rowL = gi * 16 + pcj;
          int tile = (rowL >> 5) * 2 + (pb >> 5);
          int rL   = rowL & 31;
          float s = bias4[gi];
#pragma unroll
          for (int ksi = 0; ksi < 4; ++ksi)
            s += g_par[(size_t)((ksi * 4 + tile) * 32 + (pb & 31)) * GSTR + rL];
          gt[gi] = s;
        }
        float iv = 1.f / (1.f + expf(-gt[0]));
        float fv = 1.f / (1.f + expf(-gt[1]));
        float gv = tanhf(gt[2]);
        float ov = 1.f / (1.f + expf(-gt[3]));
        creg = fv * creg + iv * gv;
        float hv = ov * tanhf(creg);
        _Float16 hf = (_Float16)hv;
        __hip_atomic_store(
            &ring[(size_t)(l * 2 + (t & 1)) * (B * H) + pb * H + j0 + pcj],
            __builtin_bit_cast(unsigned short, hf),
            __ATOMIC_RELAXED, __HIP_MEMORY_SCOPE_AGENT);
        if (l == NL - 1 && t == T - 1)
          h5[pb * H + j0 + pcj] = hv;    // f32 copy for FC precision
      }
      __syncthreads();   // drain publish stores before flagging
    }

    if (tid == 0)
      __hip_atomic_store(&flags[blk * FSTRIDE], (unsigned)(g + 1),
                         __ATOMIC_RELAXED, __HIP_MEMORY_SCOPE_AGENT);
  }
}

// ===========================================================================
// Final FC on h_5(T-1) (f32 side buffer)
// ===========================================================================
__global__ void __launch_bounds__(640) fc_kernel(
    const float* __restrict__ h5, const float* __restrict__ w,
    const float* __restrict__ bias, float* __restrict__ out)
{
  int tid = threadIdx.x;
  if (tid >= 640) return;
  int b = tid / 10, o = tid - b * 10;
  const float* yr = h5 + (size_t)b * H;
  const float* wr = w + (size_t)o * H;
  float acc = bias[o];
  for (int k = 0; k < H; ++k) acc = fmaf(yr[k], wr[k], acc);
  out[b * 10 + o] = acc;
}

extern "C" void kernel_launch(void* const* d_in, const int* in_sizes, int n_in,
                              void* d_out, int out_size, void* d_ws,
                              size_t ws_size, hipStream_t stream)
{
  const float* x    = (const float*)d_in[0];
  const float* Wih0 = (const float*)d_in[1];
  const float* WihR = (const float*)d_in[2];
  const float* Whh  = (const float*)d_in[3];
  const float* bih  = (const float*)d_in[4];
  const float* bhh  = (const float*)d_in[5];
  const float* fcw  = (const float*)d_in[6];
  const float* fcb  = (const float*)d_in[7];
  float* out = (float*)d_out;

  // ws: [0,16K) flags; ring f16[6][2][B][H] (768 KB); h5buf f32[B][H]
  unsigned* flags = (unsigned*)d_ws;
  unsigned short* ring = (unsigned short*)((char*)d_ws + 16384);
  float* h5buf = (float*)((char*)d_ws + 16384 + (size_t)NL * 2 * B * H * 2);

  hipMemsetAsync(d_ws, 0, 16384, stream);   // flags monotonic within a call

  lstm_pipe<<<NBLK_P, 1024, 0, stream>>>(x, Wih0, WihR, Whh, bih, bhh,
                                         ring, h5buf, flags);
  fc_kernel<<<1, 640, 0, stream>>>(h5buf, fcw, fcb, out);
}